// Round 9
// baseline (1986.239 us; speedup 1.0000x reference)
//
#include <hip/hip_runtime.h>
#include <cstdint>
#include <cmath>

#define S_LEN 1024
#define BATCH 64
#define IN_SZ 256
#define HID 512
#define OUT_SZ 256
#define WIH_LD 768  // W_ih leading dim = IN_SZ + HID
#define BH (BATCH * HID)            // 32768
#define XP_FLOATS (S_LEN * BH)      // 33,554,432 floats (128 MB)

// Weight pair-index space: p = k/2, p in [0,256). Per output row j (0..511):
//   p in [0,176)    -> VGPR/AGPR-resident (wregbuf[p*512 + j])
//   p in [176,200)  -> LDS-resident, packed uint2 (wldsbuf: [(pp*512+j)*2 + odd])
//   p in [200,256)  -> streamed/step      (wstr uint4: group g=(p-200)/4)
#define P_REG 176
#define P_LDS 24
#define P_STR_G 14   // 14 groups x 4 pairs = 56 pairs

// ws word layout after xp (wbase = ws + XP_FLOATS):
//  [0, 28672)          wstr      (rnn; dead after rnn)
//  [28672, 118784)     wregbuf   (rnn; dead after rnn)
//  [118784, 131072)    wldsbuf   (rnn; dead after rnn)
//  [131072, 196608)    wpk       (xproj B-fragments, 16384 uint4 = 256 KB)
//  overlays (used only after rnn completes):
//  [0, 65536)          sc_g[64][1024]
//  [65536, 98304)      ctx_g[64][512]

typedef _Float16 h2v __attribute__((ext_vector_type(2)));
typedef _Float16 f16x8 __attribute__((ext_vector_type(8)));
typedef float f32x4 __attribute__((ext_vector_type(4)));

__device__ __forceinline__ float dot2p(unsigned int a, unsigned int b, float c) {
#if __has_builtin(__builtin_amdgcn_fdot2)
    return __builtin_amdgcn_fdot2(__builtin_bit_cast(h2v, a),
                                  __builtin_bit_cast(h2v, b), c, false);
#else
    h2v av = __builtin_bit_cast(h2v, a);
    h2v bv = __builtin_bit_cast(h2v, b);
    return c + (float)av.x * (float)bv.x + (float)av.y * (float)bv.y;
#endif
}

__global__ __launch_bounds__(256) void pack_w(const float* __restrict__ W_ih,
                                              unsigned int* __restrict__ wstr,
                                              unsigned int* __restrict__ wregbuf,
                                              unsigned int* __restrict__ wldsbuf) {
    int idx = blockIdx.x * 256 + threadIdx.x;   // 0..131071
    int p = idx & 255;
    int j = idx >> 8;
    const float* src = W_ih + (size_t)j * WIH_LD + IN_SZ + 2 * p;
    unsigned short lo = __builtin_bit_cast(unsigned short, (_Float16)src[0]);
    unsigned short hi = __builtin_bit_cast(unsigned short, (_Float16)src[1]);
    unsigned int u = (unsigned int)lo | ((unsigned int)hi << 16);
    if (p < P_REG) {
        wregbuf[p * 512 + j] = u;
    } else if (p < P_REG + P_LDS) {
        int pp = (p - P_REG) >> 1;
        wldsbuf[(pp * 512 + j) * 2 + (p & 1)] = u;   // uint2-packed per j
    } else {
        int q = p - (P_REG + P_LDS);
        wstr[((q >> 2) * 512 + j) * 4 + (q & 3)] = u;
    }
}

// Pack Wx (W_ih[:, 0:256]) into MFMA B-fragment layout, f16.
__global__ __launch_bounds__(256) void pack_wf16(const float* __restrict__ W_ih,
                                                 uint4* __restrict__ wpk) {
    int idx = blockIdx.x * 256 + threadIdx.x;   // 0..16383
    if (idx >= 16384) return;
    int nt   = idx >> 9;
    int ks   = (idx >> 6) & 7;
    int lane = idx & 63;
    int n  = nt * 16 + (lane & 15);
    int kb = ks * 32 + (lane >> 4) * 8;
    const float* src = W_ih + (size_t)n * WIH_LD + kb;
    union { uint4 u; _Float16 h[8]; } v;
#pragma unroll
    for (int i = 0; i < 8; ++i) v.h[i] = (_Float16)src[i];
    wpk[idx] = v.u;
}

// xp[s][b][h] = dot(x[b][s][:], Wx[h][:]) + b_ih[h], via f16 MFMA (fp32 accum).
#define AH_LD 264   // 256 + 8-half pad
__global__ __launch_bounds__(256) void xproj_mfma(const float* __restrict__ x,
                                                  const uint4* __restrict__ wpk,
                                                  const float* __restrict__ b_ih,
                                                  float* __restrict__ xp) {
    const int s    = blockIdx.x;
    const int half = blockIdx.y;
    const int tid  = threadIdx.x;
    __shared__ __align__(16) _Float16 Ah[32 * AH_LD];
    __shared__ float bsh[HID];
    bsh[tid] = b_ih[tid];
    bsh[tid + 256] = b_ih[tid + 256];
    {
        int r  = tid >> 3;
        int c0 = (tid & 7) * 32;
        const float4* s4 = (const float4*)(x + ((size_t)(half * 32 + r) * S_LEN + s) * IN_SZ + c0);
        _Float16* dst = &Ah[r * AH_LD + c0];
#pragma unroll
        for (int i = 0; i < 8; ++i) {
            float4 v = s4[i];
            dst[4 * i + 0] = (_Float16)v.x;
            dst[4 * i + 1] = (_Float16)v.y;
            dst[4 * i + 2] = (_Float16)v.z;
            dst[4 * i + 3] = (_Float16)v.w;
        }
    }
    __syncthreads();
    const int lane = tid & 63;
    const int w    = tid >> 6;
    const int mt   = w & 1;
    const int ntb  = (w >> 1) * 16;
    f16x8 areg[8];
#pragma unroll
    for (int ks = 0; ks < 8; ++ks)
        areg[ks] = *(const f16x8*)&Ah[(mt * 16 + (lane & 15)) * AH_LD + ks * 32 + (lane >> 4) * 8];
    const int brow  = half * 32 + mt * 16 + (lane >> 4) * 4;
    const int ncol0 = lane & 15;
    for (int nt2 = 0; nt2 < 16; ++nt2) {
        int nt = ntb + nt2;
        const uint4* bp = wpk + (size_t)nt * 8 * 64 + lane;
        f32x4 acc = {0.f, 0.f, 0.f, 0.f};
#pragma unroll
        for (int ks = 0; ks < 8; ++ks) {
            uint4 bu = bp[ks * 64];
            acc = __builtin_amdgcn_mfma_f32_16x16x32_f16(
                areg[ks], __builtin_bit_cast(f16x8, bu), acc, 0, 0, 0);
        }
        int n = nt * 16 + ncol0;
        float bias = bsh[n];
        float* outp = xp + (size_t)s * BH + (size_t)brow * HID + n;
#pragma unroll
        for (int r = 0; r < 4; ++r) outp[(size_t)r * HID] = acc[r] + bias;
    }
}

// Recurrence: one WG (512 thr, 8 waves, 2/SIMD) per batch. R7 body with ONE
// change: h-state broadcast reads widened b32 -> b64 (uint2 = 2 pairs/load)
// and the LDS weight tier packed as uint2 — halves LDS-pipe instructions
// (the binding resource per the R8 cycle model: ~2240 -> ~1250 insts/CU/step).
__global__ __launch_bounds__(512, 2) void rnn_f16(const unsigned int* __restrict__ wregbuf,
                                                  const uint2* __restrict__ wldsbuf,
                                                  const uint4* __restrict__ wstr,
                                                  float* __restrict__ xp) {
    const int b = blockIdx.x;
    const int j = threadIdx.x;

    __shared__ uint2 wlds2[(P_LDS / 2) * 512];            // 48 KB, [pp][j]
    __shared__ __align__(16) unsigned short h2u[2][512];  // 2 KB, packed f16 state

    unsigned int wreg[P_REG];
#pragma unroll
    for (int p = 0; p < P_REG; ++p) wreg[p] = wregbuf[p * 512 + j];

    for (int g = j; g < (P_LDS / 2) * 512; g += 512) wlds2[g] = wldsbuf[g];
    h2u[0][j] = 0;   // f16 +0.0
    __syncthreads();

    float* col = xp + (size_t)b * HID + j;
    for (int s = 0; s < S_LEN; ++s) {
        const uint2* hq2 = (const uint2*)h2u[s & 1];   // 128 uint2 = 256 pairs
        float acc = col[(size_t)s * BH];

        uint4 sw[P_STR_G];
#pragma unroll
        for (int g = 0; g < P_STR_G; ++g) sw[g] = wstr[(size_t)g * 512 + j];

#pragma unroll
        for (int p = 0; p < P_REG / 2; ++p) {
            uint2 hv = hq2[p];
            acc = dot2p(wreg[2 * p + 0], hv.x, acc);
            acc = dot2p(wreg[2 * p + 1], hv.y, acc);
        }
#pragma unroll
        for (int pp = 0; pp < P_LDS / 2; ++pp) {
            uint2 wv = wlds2[pp * 512 + j];
            uint2 hv = hq2[P_REG / 2 + pp];
            acc = dot2p(wv.x, hv.x, acc);
            acc = dot2p(wv.y, hv.y, acc);
        }
#pragma unroll
        for (int g = 0; g < P_STR_G; ++g) {
            int pb = (P_REG + P_LDS) / 2 + 2 * g;
            uint2 h0 = hq2[pb + 0];
            uint2 h1 = hq2[pb + 1];
            acc = dot2p(sw[g].x, h0.x, acc);
            acc = dot2p(sw[g].y, h0.y, acc);
            acc = dot2p(sw[g].z, h1.x, acc);
            acc = dot2p(sw[g].w, h1.y, acc);
        }

        float v = tanhf(acc);
        col[(size_t)s * BH] = v;                                   // hidden_seq (fp32)
        h2u[(s + 1) & 1][j] = __builtin_bit_cast(unsigned short, (_Float16)v);
        // Relaxed barrier: wait LDS only; global store/loads stay in flight.
        asm volatile("s_waitcnt lgkmcnt(0)" ::: "memory");
        asm volatile("s_barrier" ::: "memory");
    }
}

// scores: sc_g[b][s] = dot(hbuf[s][b][:], hbuf[S-1][b][:]). Grid (64, 8), 256 thr.
__global__ __launch_bounds__(256) void attn_sc(const float* __restrict__ hbuf,
                                               float* __restrict__ sc_g) {
    const int b     = blockIdx.x;
    const int chunk = blockIdx.y;
    const int tid   = threadIdx.x;
    const int lane  = tid & 63;
    const int wv    = tid >> 6;
    __shared__ float fh[HID];
    fh[tid] = hbuf[(size_t)(S_LEN - 1) * BH + (size_t)b * HID + tid];
    fh[tid + 256] = hbuf[(size_t)(S_LEN - 1) * BH + (size_t)b * HID + tid + 256];
    __syncthreads();
    float4 f0 = *(const float4*)&fh[lane * 8];
    float4 f1 = *(const float4*)&fh[lane * 8 + 4];
    for (int i = 0; i < 32; ++i) {
        int s = chunk * 128 + wv * 32 + i;
        const float* hr = hbuf + (size_t)s * BH + (size_t)b * HID + lane * 8;
        float4 a0 = *(const float4*)hr;
        float4 a1 = *(const float4*)(hr + 4);
        float p = a0.x * f0.x + a0.y * f0.y + a0.z * f0.z + a0.w * f0.w +
                  a1.x * f1.x + a1.y * f1.y + a1.z * f1.z + a1.w * f1.w;
#pragma unroll
        for (int off = 32; off; off >>= 1) p += __shfl_down(p, off, 64);
        if (lane == 0) sc_g[(size_t)b * S_LEN + s] = p;
    }
}

// softmax (redundant per h-chunk) + context. Grid (64, 4), 256 thr, 128 h/WG.
__global__ __launch_bounds__(256) void attn_ctx(const float* __restrict__ hbuf,
                                                const float* __restrict__ sc_g,
                                                float* __restrict__ ctx_g) {
    const int b   = blockIdx.x;
    const int hc  = blockIdx.y * 128;
    const int tid = threadIdx.x;
    const int lane = tid & 63;
    const int wv   = tid >> 6;
    __shared__ float sc[S_LEN];
    __shared__ float red[4];
    __shared__ float part[256];
    for (int i = tid; i < S_LEN; i += 256) sc[i] = sc_g[(size_t)b * S_LEN + i];
    __syncthreads();
    float m = -1e30f;
    for (int i = tid; i < S_LEN; i += 256) m = fmaxf(m, sc[i]);
#pragma unroll
    for (int off = 32; off; off >>= 1) m = fmaxf(m, __shfl_down(m, off, 64));
    if (lane == 0) red[wv] = m;
    __syncthreads();
    m = fmaxf(fmaxf(red[0], red[1]), fmaxf(red[2], red[3]));
    float sum = 0.f;
    for (int i = tid; i < S_LEN; i += 256) {
        float e = __expf(sc[i] - m);
        sc[i] = e;
        sum += e;
    }
#pragma unroll
    for (int off = 32; off; off >>= 1) sum += __shfl_down(sum, off, 64);
    __syncthreads();
    if (lane == 0) red[wv] = sum;
    __syncthreads();
    float inv = 1.f / (red[0] + red[1] + red[2] + red[3]);
    const int h  = hc + (tid & 127);
    const int sh = tid >> 7;
    const float* hp = hbuf + (size_t)sh * 512 * BH + (size_t)b * HID + h;
    float c = 0.f;
#pragma unroll 4
    for (int s2 = 0; s2 < 512; ++s2)
        c += sc[sh * 512 + s2] * hp[(size_t)s2 * BH];
    part[tid] = c;
    __syncthreads();
    if (tid < 128) ctx_g[(size_t)b * HID + hc + tid] = (part[tid] + part[tid + 128]) * inv;
}

// out[b][o] = b_ho[o] + dot(ctx_g[b][:], W_ho[o][:]). Grid 64, 256 thr.
__global__ __launch_bounds__(256) void attn_fin(const float* __restrict__ ctx_g,
                                                const float* __restrict__ W_ho,
                                                const float* __restrict__ b_ho,
                                                float* __restrict__ out) {
    const int b   = blockIdx.x;
    const int tid = threadIdx.x;
    __shared__ float ctx[HID];
    ctx[tid] = ctx_g[(size_t)b * HID + tid];
    ctx[tid + 256] = ctx_g[(size_t)b * HID + tid + 256];
    __syncthreads();
    float o = b_ho[tid];
    const float* wr = W_ho + (size_t)tid * HID;
#pragma unroll 4
    for (int k = 0; k < HID; ++k) o += wr[k] * ctx[k];
    out[(size_t)b * OUT_SZ + tid] = o;
}

extern "C" void kernel_launch(void* const* d_in, const int* in_sizes, int n_in,
                              void* d_out, int out_size, void* d_ws, size_t ws_size,
                              hipStream_t stream) {
    const float* x    = (const float*)d_in[0];
    const float* W_ih = (const float*)d_in[1];
    const float* b_ih = (const float*)d_in[2];
    const float* W_ho = (const float*)d_in[3];
    const float* b_ho = (const float*)d_in[4];
    float* out = (float*)d_out;
    float* ws  = (float*)d_ws;

    float* xp = ws;
    unsigned int* wbase   = (unsigned int*)(ws + XP_FLOATS);
    unsigned int* wstr    = wbase;                         // 28672 words
    unsigned int* wregbuf = wbase + 28672;                 // 90112 words
    unsigned int* wldsbuf = wbase + 28672 + P_REG * 512;   // 12288 words (uint2-packed)
    uint4*        wpk     = (uint4*)(wbase + 131072);      // 16384 uint4 (256 KB)
    float*        sc_g    = (float*)wbase;                 // overlay, post-rnn
    float*        ctx_g   = (float*)(wbase + 65536);       // overlay, post-rnn

    pack_w<<<dim3(512), dim3(256), 0, stream>>>(W_ih, wstr, wregbuf, wldsbuf);
    pack_wf16<<<dim3(64), dim3(256), 0, stream>>>(W_ih, wpk);
    xproj_mfma<<<dim3(1024, 2), dim3(256), 0, stream>>>(x, wpk, b_ih, xp);
    rnn_f16<<<dim3(64), dim3(512), 0, stream>>>(wregbuf, (const uint2*)wldsbuf,
                                                (const uint4*)wstr, xp);
    attn_sc<<<dim3(64, 8), dim3(256), 0, stream>>>(xp, sc_g);
    attn_ctx<<<dim3(64, 4), dim3(256), 0, stream>>>(xp, sc_g, ctx_g);
    attn_fin<<<dim3(64), dim3(256), 0, stream>>>(ctx_g, W_ho, b_ho, out);
}

// Round 10
// 1840.750 us; speedup vs baseline: 1.0790x; 1.0790x over previous
//
#include <hip/hip_runtime.h>
#include <cstdint>
#include <cmath>

#define S_LEN 1024
#define BATCH 64
#define IN_SZ 256
#define HID 512
#define OUT_SZ 256
#define WIH_LD 768  // W_ih leading dim = IN_SZ + HID
#define BH (BATCH * HID)            // 32768
#define XP_FLOATS (S_LEN * BH)      // 33,554,432 floats (128 MB)

// Weight pair-index space: p = k/2, p in [0,256). Per output row j (0..511):
//   p in [0,176)    -> VGPR/AGPR-resident (wregbuf[p*512 + j])
//   p in [176,200)  -> LDS-resident       (wldsbuf[(p-176)*512 + j])
//   p in [200,256)  -> streamed/step      (wstr uint4: group g=(p-200)/4)
#define P_REG 176
#define P_LDS 24
#define P_STR_G 14   // 14 groups x 4 pairs = 56 pairs

// ws word layout after xp (wbase = ws + XP_FLOATS):
//  [0, 28672)          wstr      (rnn; dead after rnn)
//  [28672, 118784)     wregbuf   (rnn; dead after rnn)
//  [118784, 131072)    wldsbuf   (rnn; dead after rnn)
//  [131072, 196608)    wpk       (xproj B-fragments, 16384 uint4 = 256 KB)
//  overlays (used only after rnn completes):
//  [0, 65536)          sc_g[64][1024]
//  [65536, 98304)      ctx_g[64][512]

typedef _Float16 h2v __attribute__((ext_vector_type(2)));
typedef _Float16 f16x8 __attribute__((ext_vector_type(8)));
typedef float f32x4 __attribute__((ext_vector_type(4)));

__device__ __forceinline__ float dot2p(unsigned int a, unsigned int b, float c) {
#if __has_builtin(__builtin_amdgcn_fdot2)
    return __builtin_amdgcn_fdot2(__builtin_bit_cast(h2v, a),
                                  __builtin_bit_cast(h2v, b), c, false);
#else
    h2v av = __builtin_bit_cast(h2v, a);
    h2v bv = __builtin_bit_cast(h2v, b);
    return c + (float)av.x * (float)bv.x + (float)av.y * (float)bv.y;
#endif
}

__global__ __launch_bounds__(256) void pack_w(const float* __restrict__ W_ih,
                                              unsigned int* __restrict__ wstr,
                                              unsigned int* __restrict__ wregbuf,
                                              unsigned int* __restrict__ wldsbuf) {
    int idx = blockIdx.x * 256 + threadIdx.x;   // 0..131071
    int p = idx & 255;
    int j = idx >> 8;
    const float* src = W_ih + (size_t)j * WIH_LD + IN_SZ + 2 * p;
    unsigned short lo = __builtin_bit_cast(unsigned short, (_Float16)src[0]);
    unsigned short hi = __builtin_bit_cast(unsigned short, (_Float16)src[1]);
    unsigned int u = (unsigned int)lo | ((unsigned int)hi << 16);
    if (p < P_REG) {
        wregbuf[p * 512 + j] = u;
    } else if (p < P_REG + P_LDS) {
        wldsbuf[(p - P_REG) * 512 + j] = u;
    } else {
        int q = p - (P_REG + P_LDS);
        wstr[((q >> 2) * 512 + j) * 4 + (q & 3)] = u;
    }
}

// Pack Wx (W_ih[:, 0:256]) into MFMA B-fragment layout, f16.
__global__ __launch_bounds__(256) void pack_wf16(const float* __restrict__ W_ih,
                                                 uint4* __restrict__ wpk) {
    int idx = blockIdx.x * 256 + threadIdx.x;   // 0..16383
    if (idx >= 16384) return;
    int nt   = idx >> 9;
    int ks   = (idx >> 6) & 7;
    int lane = idx & 63;
    int n  = nt * 16 + (lane & 15);
    int kb = ks * 32 + (lane >> 4) * 8;
    const float* src = W_ih + (size_t)n * WIH_LD + kb;
    union { uint4 u; _Float16 h[8]; } v;
#pragma unroll
    for (int i = 0; i < 8; ++i) v.h[i] = (_Float16)src[i];
    wpk[idx] = v.u;
}

// xp[s][b][h] = dot(x[b][s][:], Wx[h][:]) + b_ih[h], via f16 MFMA (fp32 accum).
#define AH_LD 264   // 256 + 8-half pad
__global__ __launch_bounds__(256) void xproj_mfma(const float* __restrict__ x,
                                                  const uint4* __restrict__ wpk,
                                                  const float* __restrict__ b_ih,
                                                  float* __restrict__ xp) {
    const int s    = blockIdx.x;
    const int half = blockIdx.y;
    const int tid  = threadIdx.x;
    __shared__ __align__(16) _Float16 Ah[32 * AH_LD];
    __shared__ float bsh[HID];
    bsh[tid] = b_ih[tid];
    bsh[tid + 256] = b_ih[tid + 256];
    {
        int r  = tid >> 3;
        int c0 = (tid & 7) * 32;
        const float4* s4 = (const float4*)(x + ((size_t)(half * 32 + r) * S_LEN + s) * IN_SZ + c0);
        _Float16* dst = &Ah[r * AH_LD + c0];
#pragma unroll
        for (int i = 0; i < 8; ++i) {
            float4 v = s4[i];
            dst[4 * i + 0] = (_Float16)v.x;
            dst[4 * i + 1] = (_Float16)v.y;
            dst[4 * i + 2] = (_Float16)v.z;
            dst[4 * i + 3] = (_Float16)v.w;
        }
    }
    __syncthreads();
    const int lane = tid & 63;
    const int w    = tid >> 6;
    const int mt   = w & 1;
    const int ntb  = (w >> 1) * 16;
    f16x8 areg[8];
#pragma unroll
    for (int ks = 0; ks < 8; ++ks)
        areg[ks] = *(const f16x8*)&Ah[(mt * 16 + (lane & 15)) * AH_LD + ks * 32 + (lane >> 4) * 8];
    const int brow  = half * 32 + mt * 16 + (lane >> 4) * 4;
    const int ncol0 = lane & 15;
    for (int nt2 = 0; nt2 < 16; ++nt2) {
        int nt = ntb + nt2;
        const uint4* bp = wpk + (size_t)nt * 8 * 64 + lane;
        f32x4 acc = {0.f, 0.f, 0.f, 0.f};
#pragma unroll
        for (int ks = 0; ks < 8; ++ks) {
            uint4 bu = bp[ks * 64];
            acc = __builtin_amdgcn_mfma_f32_16x16x32_f16(
                areg[ks], __builtin_bit_cast(f16x8, bu), acc, 0, 0, 0);
        }
        int n = nt * 16 + ncol0;
        float bias = bsh[n];
        float* outp = xp + (size_t)s * BH + (size_t)brow * HID + n;
#pragma unroll
        for (int r = 0; r < 4; ++r) outp[(size_t)r * HID] = acc[r] + bias;
    }
}

// Recurrence: one WG (512 thr, 8 waves, 2/SIMD) per batch. R8 body with ONE
// logical change: the serial 256-dot2 dependency chain is split into 4
// independent accumulators, and the xp global load joins AFTER the dot2 phase
// (its L2/HBM latency overlaps the chain instead of heading it).
__global__ __launch_bounds__(512, 2) void rnn_f16(const unsigned int* __restrict__ wregbuf,
                                                  const unsigned int* __restrict__ wldsbuf,
                                                  const uint4* __restrict__ wstr,
                                                  float* __restrict__ xp) {
    const int b = blockIdx.x;
    const int j = threadIdx.x;

    __shared__ unsigned int wlds[P_LDS * 512];      // 48 KB, [p][j]
    __shared__ unsigned short h2u[2][512];          // 2 KB, packed f16 state

    unsigned int wreg[P_REG];
#pragma unroll
    for (int p = 0; p < P_REG; ++p) wreg[p] = wregbuf[p * 512 + j];

    for (int g = j; g < P_LDS * 512; g += 512) wlds[g] = wldsbuf[g];
    h2u[0][j] = 0;   // f16 +0.0
    __syncthreads();

    float* col = xp + (size_t)b * HID + j;
    for (int s = 0; s < S_LEN; ++s) {
        const unsigned int* hq = (const unsigned int*)h2u[s & 1];  // 256 pairs
        float xpv = col[(size_t)s * BH];   // issued here, consumed after the chain

        uint4 sw[P_STR_G];
#pragma unroll
        for (int g = 0; g < P_STR_G; ++g) sw[g] = wstr[(size_t)g * 512 + j];

        float a0 = 0.f, a1 = 0.f, a2 = 0.f, a3 = 0.f;
#pragma unroll
        for (int p = 0; p < P_REG; p += 4) {
            a0 = dot2p(wreg[p + 0], hq[p + 0], a0);
            a1 = dot2p(wreg[p + 1], hq[p + 1], a1);
            a2 = dot2p(wreg[p + 2], hq[p + 2], a2);
            a3 = dot2p(wreg[p + 3], hq[p + 3], a3);
        }
#pragma unroll
        for (int p = 0; p < P_LDS; p += 4) {
            a0 = dot2p(wlds[(p + 0) * 512 + j], hq[P_REG + p + 0], a0);
            a1 = dot2p(wlds[(p + 1) * 512 + j], hq[P_REG + p + 1], a1);
            a2 = dot2p(wlds[(p + 2) * 512 + j], hq[P_REG + p + 2], a2);
            a3 = dot2p(wlds[(p + 3) * 512 + j], hq[P_REG + p + 3], a3);
        }
#pragma unroll
        for (int g = 0; g < P_STR_G; ++g) {
            int pb = P_REG + P_LDS + 4 * g;
            a0 = dot2p(sw[g].x, hq[pb + 0], a0);
            a1 = dot2p(sw[g].y, hq[pb + 1], a1);
            a2 = dot2p(sw[g].z, hq[pb + 2], a2);
            a3 = dot2p(sw[g].w, hq[pb + 3], a3);
        }

        float v = tanhf(((a0 + a1) + (a2 + a3)) + xpv);
        col[(size_t)s * BH] = v;                                   // hidden_seq (fp32)
        h2u[(s + 1) & 1][j] = __builtin_bit_cast(unsigned short, (_Float16)v);
        // Relaxed barrier: wait LDS only; global store/loads stay in flight.
        asm volatile("s_waitcnt lgkmcnt(0)" ::: "memory");
        asm volatile("s_barrier" ::: "memory");
    }
}

// scores: sc_g[b][s] = dot(hbuf[s][b][:], hbuf[S-1][b][:]). Grid (64, 8), 256 thr.
__global__ __launch_bounds__(256) void attn_sc(const float* __restrict__ hbuf,
                                               float* __restrict__ sc_g) {
    const int b     = blockIdx.x;
    const int chunk = blockIdx.y;
    const int tid   = threadIdx.x;
    const int lane  = tid & 63;
    const int wv    = tid >> 6;
    __shared__ float fh[HID];
    fh[tid] = hbuf[(size_t)(S_LEN - 1) * BH + (size_t)b * HID + tid];
    fh[tid + 256] = hbuf[(size_t)(S_LEN - 1) * BH + (size_t)b * HID + tid + 256];
    __syncthreads();
    float4 f0 = *(const float4*)&fh[lane * 8];
    float4 f1 = *(const float4*)&fh[lane * 8 + 4];
    for (int i = 0; i < 32; ++i) {
        int s = chunk * 128 + wv * 32 + i;
        const float* hr = hbuf + (size_t)s * BH + (size_t)b * HID + lane * 8;
        float4 a0 = *(const float4*)hr;
        float4 a1 = *(const float4*)(hr + 4);
        float p = a0.x * f0.x + a0.y * f0.y + a0.z * f0.z + a0.w * f0.w +
                  a1.x * f1.x + a1.y * f1.y + a1.z * f1.z + a1.w * f1.w;
#pragma unroll
        for (int off = 32; off; off >>= 1) p += __shfl_down(p, off, 64);
        if (lane == 0) sc_g[(size_t)b * S_LEN + s] = p;
    }
}

// softmax (redundant per h-chunk) + context. Grid (64, 4), 256 thr, 128 h/WG.
__global__ __launch_bounds__(256) void attn_ctx(const float* __restrict__ hbuf,
                                                const float* __restrict__ sc_g,
                                                float* __restrict__ ctx_g) {
    const int b   = blockIdx.x;
    const int hc  = blockIdx.y * 128;
    const int tid = threadIdx.x;
    const int lane = tid & 63;
    const int wv   = tid >> 6;
    __shared__ float sc[S_LEN];
    __shared__ float red[4];
    __shared__ float part[256];
    for (int i = tid; i < S_LEN; i += 256) sc[i] = sc_g[(size_t)b * S_LEN + i];
    __syncthreads();
    float m = -1e30f;
    for (int i = tid; i < S_LEN; i += 256) m = fmaxf(m, sc[i]);
#pragma unroll
    for (int off = 32; off; off >>= 1) m = fmaxf(m, __shfl_down(m, off, 64));
    if (lane == 0) red[wv] = m;
    __syncthreads();
    m = fmaxf(fmaxf(red[0], red[1]), fmaxf(red[2], red[3]));
    float sum = 0.f;
    for (int i = tid; i < S_LEN; i += 256) {
        float e = __expf(sc[i] - m);
        sc[i] = e;
        sum += e;
    }
#pragma unroll
    for (int off = 32; off; off >>= 1) sum += __shfl_down(sum, off, 64);
    __syncthreads();
    if (lane == 0) red[wv] = sum;
    __syncthreads();
    float inv = 1.f / (red[0] + red[1] + red[2] + red[3]);
    const int h  = hc + (tid & 127);
    const int sh = tid >> 7;
    const float* hp = hbuf + (size_t)sh * 512 * BH + (size_t)b * HID + h;
    float c = 0.f;
#pragma unroll 4
    for (int s2 = 0; s2 < 512; ++s2)
        c += sc[sh * 512 + s2] * hp[(size_t)s2 * BH];
    part[tid] = c;
    __syncthreads();
    if (tid < 128) ctx_g[(size_t)b * HID + hc + tid] = (part[tid] + part[tid + 128]) * inv;
}

// out[b][o] = b_ho[o] + dot(ctx_g[b][:], W_ho[o][:]). Grid 64, 256 thr.
__global__ __launch_bounds__(256) void attn_fin(const float* __restrict__ ctx_g,
                                                const float* __restrict__ W_ho,
                                                const float* __restrict__ b_ho,
                                                float* __restrict__ out) {
    const int b   = blockIdx.x;
    const int tid = threadIdx.x;
    __shared__ float ctx[HID];
    ctx[tid] = ctx_g[(size_t)b * HID + tid];
    ctx[tid + 256] = ctx_g[(size_t)b * HID + tid + 256];
    __syncthreads();
    float o = b_ho[tid];
    const float* wr = W_ho + (size_t)tid * HID;
#pragma unroll 4
    for (int k = 0; k < HID; ++k) o += wr[k] * ctx[k];
    out[(size_t)b * OUT_SZ + tid] = o;
}

extern "C" void kernel_launch(void* const* d_in, const int* in_sizes, int n_in,
                              void* d_out, int out_size, void* d_ws, size_t ws_size,
                              hipStream_t stream) {
    const float* x    = (const float*)d_in[0];
    const float* W_ih = (const float*)d_in[1];
    const float* b_ih = (const float*)d_in[2];
    const float* W_ho = (const float*)d_in[3];
    const float* b_ho = (const float*)d_in[4];
    float* out = (float*)d_out;
    float* ws  = (float*)d_ws;

    float* xp = ws;
    unsigned int* wbase   = (unsigned int*)(ws + XP_FLOATS);
    unsigned int* wstr    = wbase;                         // 28672 words
    unsigned int* wregbuf = wbase + 28672;                 // 90112 words
    unsigned int* wldsbuf = wbase + 28672 + P_REG * 512;   // 12288 words
    uint4*        wpk     = (uint4*)(wbase + 131072);      // 16384 uint4 (256 KB)
    float*        sc_g    = (float*)wbase;                 // overlay, post-rnn
    float*        ctx_g   = (float*)(wbase + 65536);       // overlay, post-rnn

    pack_w<<<dim3(512), dim3(256), 0, stream>>>(W_ih, wstr, wregbuf, wldsbuf);
    pack_wf16<<<dim3(64), dim3(256), 0, stream>>>(W_ih, wpk);
    xproj_mfma<<<dim3(1024, 2), dim3(256), 0, stream>>>(x, wpk, b_ih, xp);
    rnn_f16<<<dim3(64), dim3(512), 0, stream>>>(wregbuf, wldsbuf, (const uint4*)wstr, xp);
    attn_sc<<<dim3(64, 8), dim3(256), 0, stream>>>(xp, sc_g);
    attn_ctx<<<dim3(64, 4), dim3(256), 0, stream>>>(xp, sc_g, ctx_g);
    attn_fin<<<dim3(64), dim3(256), 0, stream>>>(ctx_g, W_ho, b_ho, out);
}